// Round 4
// baseline (390.559 us; speedup 1.0000x reference)
//
#include <hip/hip_runtime.h>
#include <math.h>

#define I_DIM 1025
#define J_DIM 1024
#define K_DIM 8
#define NCH 64
#define CHB 17     // ceil(1025/64)
#define N_ITER 10
#define EPS 1e-20f
#define REG 1e-6f
#define MODE_CD  1
#define MODE_NMF 2

__device__ __forceinline__ float2 cmul(float2 a, float2 b){
  return make_float2(a.x*b.x - a.y*b.y, a.x*b.y + a.y*b.x);
}
__device__ __forceinline__ float2 cadd(float2 a, float2 b){
  return make_float2(a.x+b.x, a.y+b.y);
}
__device__ __forceinline__ float2 csub(float2 a, float2 b){
  return make_float2(a.x-b.x, a.y-b.y);
}
__device__ __forceinline__ float2 cconj(float2 a){ return make_float2(a.x, -a.y); }
__device__ __forceinline__ float2 cscale(float2 a, float s){ return make_float2(a.x*s, a.y*s); }
__device__ __forceinline__ float2 cdivc(float2 a, float2 d){
  float inv = 1.0f/(d.x*d.x + d.y*d.y);
  return make_float2((a.x*d.x + a.y*d.y)*inv, (a.y*d.x - a.x*d.y)*inv);
}

// ---- init T/V internal copies (layout [n][...]) and W = identity ----
__global__ void k_init(const float* __restrict__ T0, const float* __restrict__ V0,
                       float* __restrict__ Tw, float* __restrict__ Vw, float2* __restrict__ Wm){
  int tid = blockIdx.x*blockDim.x + threadIdx.x;
  if (tid < 2*I_DIM*K_DIM){
    int n = tid/(I_DIM*K_DIM), rem = tid%(I_DIM*K_DIM);
    int i = rem/K_DIM, k = rem%K_DIM;
    Tw[tid] = T0[(i*K_DIM+k)*2 + n];              // T0 [I,K,M]
  }
  if (tid < 2*K_DIM*J_DIM){
    int n = tid/(K_DIM*J_DIM), rem = tid%(K_DIM*J_DIM);
    int k = rem/J_DIM, j = rem%J_DIM;
    Vw[tid] = V0[(k*J_DIM+j)*2 + n];              // V0 [K,J,M]
  }
  if (tid < I_DIM*4){
    int rc = tid & 3;                              // n*2+m
    Wm[tid] = make_float2((rc==0||rc==3)?1.0f:0.0f, 0.0f);
  }
}

// ---- transpose X [M,J,I,2] -> Xc4 [I][J] float4 = (x0.re,x0.im,x1.re,x1.im) ----
__global__ void k_txpose(const float2* __restrict__ Xin, float4* __restrict__ Xc4){
  __shared__ float4 tile[32][33];
  int i0 = blockIdx.x*32, j0 = blockIdx.y*32;
  int tx = threadIdx.x, ty = threadIdx.y;
  #pragma unroll
  for (int r=0;r<4;r++){
    int jl = ty + r*8; int i = i0 + tx;
    if (i < I_DIM){
      float2 a = Xin[(size_t)(0*J_DIM + j0 + jl)*I_DIM + i];
      float2 b = Xin[(size_t)(1*J_DIM + j0 + jl)*I_DIM + i];
      tile[jl][tx] = make_float4(a.x, a.y, b.x, b.y);
    }
  }
  __syncthreads();
  #pragma unroll
  for (int r=0;r<4;r++){
    int il = ty + r*8; int i = i0 + il;
    if (i < I_DIM) Xc4[(size_t)i*J_DIM + j0 + tx] = tile[tx][il];
  }
}

// ---- fused: [CD + 2x2 solve -> W_i] then [NMF stage A for next iter] ----
// mode bits: MODE_CD: compute D from r=T.V, solve, update W (else load W)
//            MODE_NMF: compute P,Q and T-row update using current W
// Key reuse: r = T@V serves both the covariance weights (q=1/(r+eps)) of the
// CD step and the NMF Rn of the following iteration (T,V,Y unchanged between).
__global__ __launch_bounds__(256) void k_cda(const float4* __restrict__ Xc4,
      float* __restrict__ Tw, const float* __restrict__ Vw,
      float2* __restrict__ Wm, float* __restrict__ P, float* __restrict__ Q, int mode){
  int i = blockIdx.x, tid = threadIdx.x;
  int n = tid >> 7, jl = tid & 127;     // waves 0,1 -> n=0; waves 2,3 -> n=1
  __shared__ float redD[4][4];
  __shared__ float redT[4][16];
  __shared__ float wsh[8];

  float t[8];
  {
    const float4* tp = (const float4*)&Tw[(size_t)(n*I_DIM+i)*K_DIM];
    float4 ta = tp[0], tb = tp[1];
    t[0]=ta.x; t[1]=ta.y; t[2]=ta.z; t[3]=ta.w;
    t[4]=tb.x; t[5]=tb.y; t[6]=tb.z; t[7]=tb.w;
  }
  // r for 8 consecutive j's owned by this thread
  float r_s[8] = {0,0,0,0,0,0,0,0};
  #pragma unroll
  for (int k=0;k<8;k++){
    const float4* vp = (const float4*)&Vw[(size_t)(n*K_DIM+k)*J_DIM + jl*8];
    float4 va = vp[0], vb = vp[1];
    r_s[0]+=t[k]*va.x; r_s[1]+=t[k]*va.y; r_s[2]+=t[k]*va.z; r_s[3]+=t[k]*va.w;
    r_s[4]+=t[k]*vb.x; r_s[5]+=t[k]*vb.y; r_s[6]+=t[k]*vb.z; r_s[7]+=t[k]*vb.w;
  }

  if (mode & MODE_CD){
    float d00=0.0f, d11=0.0f, dre=0.0f, dim_=0.0f;
    #pragma unroll
    for (int s=0;s<8;s++){
      float4 x = Xc4[(size_t)i*J_DIM + jl*8 + s];
      float q = 1.0f/(r_s[s] + EPS);
      d00 += (x.x*x.x + x.y*x.y)*q;
      d11 += (x.z*x.z + x.w*x.w)*q;
      dre += (x.x*x.z + x.y*x.w)*q;   // Re(x0*conj(x1))
      dim_ += (x.y*x.z - x.x*x.w)*q;  // Im(x0*conj(x1))
    }
    #pragma unroll
    for (int off=32; off>0; off>>=1){
      d00 += __shfl_down(d00,off); d11 += __shfl_down(d11,off);
      dre += __shfl_down(dre,off); dim_ += __shfl_down(dim_,off);
    }
    {
      int lane = tid&63, wv = tid>>6;
      if (lane==0){ redD[wv][0]=d00; redD[wv][1]=d11; redD[wv][2]=dre; redD[wv][3]=dim_; }
    }
    __syncthreads();
    if (tid==0){
      const float invJ = 1.0f/(float)J_DIM;
      float D[2][4];
      #pragma unroll
      for (int c=0;c<4;c++){
        D[0][c] = (redD[0][c]+redD[1][c])*invJ;
        D[1][c] = (redD[2][c]+redD[3][c])*invJ;
      }
      float2 w00 = Wm[i*4+0], w01 = Wm[i*4+1], w10 = Wm[i*4+2], w11 = Wm[i*4+3];
      #pragma unroll
      for (int nn=0;nn<2;nn++){
        float d00_ = D[nn][0] + REG, d11_ = D[nn][1] + REG;
        float2 d01 = make_float2(D[nn][2], D[nn][3]);
        float2 d10 = cconj(d01);
        float2 A00 = cadd(cscale(w00, d00_), cmul(w01, d10));
        float2 A01 = cadd(cmul(w00, d01), cscale(w01, d11_));
        float2 A10 = cadd(cscale(w10, d00_), cmul(w11, d10));
        float2 A11 = cadd(cmul(w10, d01), cscale(w11, d11_));
        float2 det = csub(cmul(A00,A11), cmul(A01,A10));
        float2 bu0, bu1;
        if (nn==0){ bu0 = A11; bu1 = make_float2(-A10.x, -A10.y); }
        else      { bu0 = make_float2(-A01.x, -A01.y); bu1 = A00; }
        float2 b0 = cdivc(bu0, det);
        float2 b1 = cdivc(bu1, det);
        float quad = d00_*(b0.x*b0.x + b0.y*b0.y) + d11_*(b1.x*b1.x + b1.y*b1.y);
        float2 u = cmul(d01, b1);
        quad += 2.0f*(b0.x*u.x + b0.y*u.y);
        float inv = 1.0f/sqrtf(quad + EPS);
        float2 wn0 = make_float2(b0.x*inv, -b0.y*inv);
        float2 wn1 = make_float2(b1.x*inv, -b1.y*inv);
        if (nn==0){ w00=wn0; w01=wn1; } else { w10=wn0; w11=wn1; }
      }
      Wm[i*4+0]=w00; Wm[i*4+1]=w01; Wm[i*4+2]=w10; Wm[i*4+3]=w11;
      wsh[0]=w00.x; wsh[1]=w00.y; wsh[2]=w01.x; wsh[3]=w01.y;
      wsh[4]=w10.x; wsh[5]=w10.y; wsh[6]=w11.x; wsh[7]=w11.y;
    }
  } else {
    if (tid < 4){ float2 w = Wm[i*4+tid]; wsh[tid*2]=w.x; wsh[tid*2+1]=w.y; }
  }
  __syncthreads();
  if (!(mode & MODE_NMF)) return;

  float2 w0 = make_float2(wsh[n*4+0], wsh[n*4+1]);
  float2 w1 = make_float2(wsh[n*4+2], wsh[n*4+3]);
  float p_s[8], q_s[8];
  #pragma unroll
  for (int s=0;s<8;s++){
    float4 x = Xc4[(size_t)i*J_DIM + jl*8 + s];
    float yre = w0.x*x.x - w0.y*x.y + w1.x*x.z - w1.y*x.w;
    float yim = w0.x*x.y + w0.y*x.x + w1.x*x.w + w1.y*x.z;
    float y2 = yre*yre + yim*yim;
    float r = r_s[s];
    p_s[s] = y2/(r*r + EPS);
    q_s[s] = 1.0f/(r + EPS);
  }
  size_t pqb = (size_t)(n*I_DIM+i)*J_DIM + jl*8;
  *(float4*)&P[pqb]   = make_float4(p_s[0],p_s[1],p_s[2],p_s[3]);
  *(float4*)&P[pqb+4] = make_float4(p_s[4],p_s[5],p_s[6],p_s[7]);
  *(float4*)&Q[pqb]   = make_float4(q_s[0],q_s[1],q_s[2],q_s[3]);
  *(float4*)&Q[pqb+4] = make_float4(q_s[4],q_s[5],q_s[6],q_s[7]);

  float aN[8], aD[8];
  #pragma unroll
  for (int k=0;k<8;k++){
    const float4* vp = (const float4*)&Vw[(size_t)(n*K_DIM+k)*J_DIM + jl*8];
    float4 va = vp[0], vb = vp[1];
    aN[k] = p_s[0]*va.x + p_s[1]*va.y + p_s[2]*va.z + p_s[3]*va.w
          + p_s[4]*vb.x + p_s[5]*vb.y + p_s[6]*vb.z + p_s[7]*vb.w;
    aD[k] = q_s[0]*va.x + q_s[1]*va.y + q_s[2]*va.z + q_s[3]*va.w
          + q_s[4]*vb.x + q_s[5]*vb.y + q_s[6]*vb.z + q_s[7]*vb.w;
  }
  #pragma unroll
  for (int k=0;k<8;k++){
    #pragma unroll
    for (int off=32; off>0; off>>=1){
      aN[k] += __shfl_down(aN[k],off);
      aD[k] += __shfl_down(aD[k],off);
    }
  }
  {
    int lane = tid&63, wv = tid>>6;
    if (lane==0){
      #pragma unroll
      for (int k=0;k<8;k++){ redT[wv][k]=aN[k]; redT[wv][k+8]=aD[k]; }
    }
  }
  __syncthreads();
  if ((tid & 127) < 8){
    int kk = tid & 7;
    int wb = (tid>>7)*2;
    float ns = redT[wb][kk]   + redT[wb+1][kk];
    float ds = redT[wb][kk+8] + redT[wb+1][kk+8];
    size_t ti = (size_t)(n*I_DIM+i)*K_DIM + kk;
    Tw[ti] = Tw[ti]*sqrtf(ns/(ds + EPS));
  }
}

// ---- stage B: partial I-reduction for V update (uses UPDATED T, P/Q) ----
__global__ __launch_bounds__(256) void k_nmf_b(const float* __restrict__ P, const float* __restrict__ Q,
      const float* __restrict__ Tw, float* __restrict__ partN, float* __restrict__ partD){
  int n = blockIdx.z, ch = blockIdx.y;
  int j = blockIdx.x*256 + threadIdx.x;
  int i0 = ch*CHB, i1 = min(i0+CHB, I_DIM);
  float aN[8] = {0,0,0,0,0,0,0,0};
  float aD[8] = {0,0,0,0,0,0,0,0};
  #pragma unroll 4
  for (int i=i0;i<i1;i++){
    float p = P[(size_t)(n*I_DIM+i)*J_DIM + j];
    float q = Q[(size_t)(n*I_DIM+i)*J_DIM + j];
    #pragma unroll
    for (int k=0;k<8;k++){
      float t = Tw[(size_t)(n*I_DIM+i)*K_DIM + k];   // uniform -> scalar loads
      aN[k] += t*p; aD[k] += t*q;
    }
  }
  #pragma unroll
  for (int k=0;k<8;k++){
    partN[(size_t)((n*NCH+ch)*K_DIM + k)*J_DIM + j] = aN[k];
    partD[(size_t)((n*NCH+ch)*K_DIM + k)*J_DIM + j] = aD[k];
  }
}

// ---- stage B2: combine partials, scale V ----
__global__ void k_nmf_b2(const float* __restrict__ partN, const float* __restrict__ partD,
                         float* __restrict__ Vw){
  int idx = blockIdx.x*blockDim.x + threadIdx.x;  // over 2*K*J
  if (idx >= 2*K_DIM*J_DIM) return;
  int n = idx/(K_DIM*J_DIM), rem = idx%(K_DIM*J_DIM);
  float num=0.0f, den=0.0f;
  #pragma unroll 8
  for (int ch=0; ch<NCH; ch++){
    num += partN[(size_t)(n*NCH+ch)*K_DIM*J_DIM + rem];
    den += partD[(size_t)(n*NCH+ch)*K_DIM*J_DIM + rem];
  }
  Vw[idx] *= sqrtf(num/(den + EPS));
}

// ---- final: Y = W @ X, write out [N,J,I,2] (transpose via LDS tile) ----
__global__ void k_final(const float4* __restrict__ Xc4, const float2* __restrict__ Wm,
                        float2* __restrict__ out){
  __shared__ float2 yt[2][32][33];
  int i0 = blockIdx.x*32, j0 = blockIdx.y*32;
  int tx = threadIdx.x, ty = threadIdx.y;
  int j = j0 + tx;
  #pragma unroll
  for (int r=0;r<4;r++){
    int il = ty + r*8; int i = i0 + il;
    if (i < I_DIM){
      float4 x = Xc4[(size_t)i*J_DIM + j];
      #pragma unroll
      for (int n=0;n<2;n++){
        float2 a = Wm[i*4+n*2+0], b = Wm[i*4+n*2+1];
        float2 y;
        y.x = a.x*x.x - a.y*x.y + b.x*x.z - b.y*x.w;
        y.y = a.x*x.y + a.y*x.x + b.x*x.w + b.y*x.z;
        yt[n][tx][il] = y;
      }
    }
  }
  __syncthreads();
  int i = i0 + tx;
  if (i < I_DIM){
    #pragma unroll
    for (int n=0;n<2;n++){
      #pragma unroll
      for (int r=0;r<4;r++){
        int jl = ty + r*8;
        out[(size_t)(n*J_DIM + j0 + jl)*I_DIM + i] = yt[n][jl][tx];
      }
    }
  }
}

extern "C" void kernel_launch(void* const* d_in, const int* in_sizes, int n_in,
                              void* d_out, int out_size, void* d_ws, size_t ws_size,
                              hipStream_t stream){
  const float* X  = (const float*)d_in[0];   // [M,J,I,2]
  const float* T0 = (const float*)d_in[1];   // [I,K,M]
  const float* V0 = (const float*)d_in[2];   // [K,J,M]

  char* ws = (char*)d_ws;
  size_t off = 0;
  auto alloc = [&](size_t bytes)->char*{
    char* p = ws + off; off += (bytes + 255) & ~(size_t)255; return p;
  };
  float4* Xc4  = (float4*)alloc((size_t)I_DIM*J_DIM*sizeof(float4));
  float*  P    = (float*) alloc((size_t)2*I_DIM*J_DIM*sizeof(float));
  float*  Q    = (float*) alloc((size_t)2*I_DIM*J_DIM*sizeof(float));
  float*  Tw   = (float*) alloc((size_t)2*I_DIM*K_DIM*sizeof(float));
  float*  Vw   = (float*) alloc((size_t)2*K_DIM*J_DIM*sizeof(float));
  float2* Wm   = (float2*)alloc((size_t)I_DIM*4*sizeof(float2));
  float*  ptN  = (float*) alloc((size_t)2*NCH*K_DIM*J_DIM*sizeof(float));
  float*  ptD  = (float*) alloc((size_t)2*NCH*K_DIM*J_DIM*sizeof(float));

  k_init<<<65, 256, 0, stream>>>(T0, V0, Tw, Vw, Wm);
  k_txpose<<<dim3(33,32), dim3(32,8), 0, stream>>>((const float2*)X, Xc4);
  // A0: NMF stage-A of body 0 (W = identity)
  k_cda<<<I_DIM, 256, 0, stream>>>(Xc4, Tw, Vw, Wm, P, Q, MODE_NMF);
  for (int it=0; it<N_ITER; it++){
    k_nmf_b<<<dim3(4,NCH,2), 256, 0, stream>>>(P, Q, Tw, ptN, ptD);
    k_nmf_b2<<<64, 256, 0, stream>>>(ptN, ptD, Vw);
    int mode = (it < N_ITER-1) ? (MODE_CD|MODE_NMF) : MODE_CD;
    k_cda<<<I_DIM, 256, 0, stream>>>(Xc4, Tw, Vw, Wm, P, Q, mode);
  }
  k_final<<<dim3(33,32), dim3(32,8), 0, stream>>>(Xc4, Wm, (float2*)d_out);
}

// Round 5
// 331.909 us; speedup vs baseline: 1.1767x; 1.1767x over previous
//
#include <hip/hip_runtime.h>
#include <math.h>

#define I_DIM 1025
#define J_DIM 1024
#define K_DIM 8
#define N_ITER 10
#define EPS 1e-20f
#define REG 1e-6f
#define MODE_CD  1
#define MODE_NMF 2

__device__ __forceinline__ float2 cmul(float2 a, float2 b){
  return make_float2(a.x*b.x - a.y*b.y, a.x*b.y + a.y*b.x);
}
__device__ __forceinline__ float2 cadd(float2 a, float2 b){
  return make_float2(a.x+b.x, a.y+b.y);
}
__device__ __forceinline__ float2 csub(float2 a, float2 b){
  return make_float2(a.x-b.x, a.y-b.y);
}
__device__ __forceinline__ float2 cconj(float2 a){ return make_float2(a.x, -a.y); }
__device__ __forceinline__ float2 cscale(float2 a, float s){ return make_float2(a.x*s, a.y*s); }
__device__ __forceinline__ float2 cdivc(float2 a, float2 d){
  float inv = 1.0f/(d.x*d.x + d.y*d.y);
  return make_float2((a.x*d.x + a.y*d.y)*inv, (a.y*d.x - a.x*d.y)*inv);
}

// ---- init T/V internal copies (layout [n][...]) and W = identity ----
__global__ void k_init(const float* __restrict__ T0, const float* __restrict__ V0,
                       float* __restrict__ Tw, float* __restrict__ Vw, float2* __restrict__ Wm){
  int tid = blockIdx.x*blockDim.x + threadIdx.x;
  if (tid < 2*I_DIM*K_DIM){
    int n = tid/(I_DIM*K_DIM), rem = tid%(I_DIM*K_DIM);
    int i = rem/K_DIM, k = rem%K_DIM;
    Tw[tid] = T0[(i*K_DIM+k)*2 + n];              // T0 [I,K,M]
  }
  if (tid < 2*K_DIM*J_DIM){
    int n = tid/(K_DIM*J_DIM), rem = tid%(K_DIM*J_DIM);
    int k = rem/J_DIM, j = rem%J_DIM;
    Vw[tid] = V0[(k*J_DIM+j)*2 + n];              // V0 [K,J,M]
  }
  if (tid < I_DIM*4){
    int rc = tid & 3;                              // n*2+m
    Wm[tid] = make_float2((rc==0||rc==3)?1.0f:0.0f, 0.0f);
  }
}

// ---- transpose X [M,J,I,2] -> Xc4 [I][J] float4 = (x0.re,x0.im,x1.re,x1.im) ----
__global__ void k_txpose(const float2* __restrict__ Xin, float4* __restrict__ Xc4){
  __shared__ float4 tile[32][33];
  int i0 = blockIdx.x*32, j0 = blockIdx.y*32;
  int tx = threadIdx.x, ty = threadIdx.y;
  #pragma unroll
  for (int r=0;r<4;r++){
    int jl = ty + r*8; int i = i0 + tx;
    if (i < I_DIM){
      float2 a = Xin[(size_t)(0*J_DIM + j0 + jl)*I_DIM + i];
      float2 b = Xin[(size_t)(1*J_DIM + j0 + jl)*I_DIM + i];
      tile[jl][tx] = make_float4(a.x, a.y, b.x, b.y);
    }
  }
  __syncthreads();
  #pragma unroll
  for (int r=0;r<4;r++){
    int il = ty + r*8; int i = i0 + il;
    if (i < I_DIM) Xc4[(size_t)i*J_DIM + j0 + tx] = tile[tx][il];
  }
}

// ---- fused: [CD + 2x2 solve -> W_i] then [NMF T-update for next body] ----
// No P/Q materialization: saves T_old (for k_vupd's p,q recompute) instead.
// X row kept in registers across both phases (read once).
__global__ __launch_bounds__(256) void k_cda(const float4* __restrict__ Xc4,
      float* __restrict__ Tw, float* __restrict__ Told, const float* __restrict__ Vw,
      float2* __restrict__ Wm, int mode){
  int i = blockIdx.x, tid = threadIdx.x;
  int n = tid >> 7, jl = tid & 127;     // waves 0,1 -> n=0; waves 2,3 -> n=1
  __shared__ float redD[4][4];
  __shared__ float redT[4][16];
  __shared__ float wsh[8];

  float t[8];
  {
    const float4* tp = (const float4*)&Tw[(size_t)(n*I_DIM+i)*K_DIM];
    float4 ta = tp[0], tb = tp[1];
    t[0]=ta.x; t[1]=ta.y; t[2]=ta.z; t[3]=ta.w;
    t[4]=tb.x; t[5]=tb.y; t[6]=tb.z; t[7]=tb.w;
  }
  // r = T.V for the 8 consecutive j's owned by this thread
  float r_s[8] = {0,0,0,0,0,0,0,0};
  #pragma unroll
  for (int k=0;k<8;k++){
    const float4* vp = (const float4*)&Vw[(size_t)(n*K_DIM+k)*J_DIM + jl*8];
    float4 va = vp[0], vb = vp[1];
    r_s[0]+=t[k]*va.x; r_s[1]+=t[k]*va.y; r_s[2]+=t[k]*va.z; r_s[3]+=t[k]*va.w;
    r_s[4]+=t[k]*vb.x; r_s[5]+=t[k]*vb.y; r_s[6]+=t[k]*vb.z; r_s[7]+=t[k]*vb.w;
  }
  // X row in registers (shared by CD and NMF phases)
  float4 x_s[8];
  #pragma unroll
  for (int s=0;s<8;s++) x_s[s] = Xc4[(size_t)i*J_DIM + jl*8 + s];

  if (mode & MODE_CD){
    float d00=0.0f, d11=0.0f, dre=0.0f, dim_=0.0f;
    #pragma unroll
    for (int s=0;s<8;s++){
      float4 x = x_s[s];
      float q = 1.0f/(r_s[s] + EPS);
      d00 += (x.x*x.x + x.y*x.y)*q;
      d11 += (x.z*x.z + x.w*x.w)*q;
      dre += (x.x*x.z + x.y*x.w)*q;   // Re(x0*conj(x1))
      dim_ += (x.y*x.z - x.x*x.w)*q;  // Im(x0*conj(x1))
    }
    #pragma unroll
    for (int off=32; off>0; off>>=1){
      d00 += __shfl_down(d00,off); d11 += __shfl_down(d11,off);
      dre += __shfl_down(dre,off); dim_ += __shfl_down(dim_,off);
    }
    {
      int lane = tid&63, wv = tid>>6;
      if (lane==0){ redD[wv][0]=d00; redD[wv][1]=d11; redD[wv][2]=dre; redD[wv][3]=dim_; }
    }
    __syncthreads();
    if (tid==0){
      const float invJ = 1.0f/(float)J_DIM;
      float D[2][4];
      #pragma unroll
      for (int c=0;c<4;c++){
        D[0][c] = (redD[0][c]+redD[1][c])*invJ;
        D[1][c] = (redD[2][c]+redD[3][c])*invJ;
      }
      float2 w00 = Wm[i*4+0], w01 = Wm[i*4+1], w10 = Wm[i*4+2], w11 = Wm[i*4+3];
      #pragma unroll
      for (int nn=0;nn<2;nn++){
        float d00_ = D[nn][0] + REG, d11_ = D[nn][1] + REG;
        float2 d01 = make_float2(D[nn][2], D[nn][3]);
        float2 d10 = cconj(d01);
        float2 A00 = cadd(cscale(w00, d00_), cmul(w01, d10));
        float2 A01 = cadd(cmul(w00, d01), cscale(w01, d11_));
        float2 A10 = cadd(cscale(w10, d00_), cmul(w11, d10));
        float2 A11 = cadd(cmul(w10, d01), cscale(w11, d11_));
        float2 det = csub(cmul(A00,A11), cmul(A01,A10));
        float2 bu0, bu1;
        if (nn==0){ bu0 = A11; bu1 = make_float2(-A10.x, -A10.y); }
        else      { bu0 = make_float2(-A01.x, -A01.y); bu1 = A00; }
        float2 b0 = cdivc(bu0, det);
        float2 b1 = cdivc(bu1, det);
        float quad = d00_*(b0.x*b0.x + b0.y*b0.y) + d11_*(b1.x*b1.x + b1.y*b1.y);
        float2 u = cmul(d01, b1);
        quad += 2.0f*(b0.x*u.x + b0.y*u.y);
        float inv = 1.0f/sqrtf(quad + EPS);
        float2 wn0 = make_float2(b0.x*inv, -b0.y*inv);
        float2 wn1 = make_float2(b1.x*inv, -b1.y*inv);
        if (nn==0){ w00=wn0; w01=wn1; } else { w10=wn0; w11=wn1; }
      }
      Wm[i*4+0]=w00; Wm[i*4+1]=w01; Wm[i*4+2]=w10; Wm[i*4+3]=w11;
      wsh[0]=w00.x; wsh[1]=w00.y; wsh[2]=w01.x; wsh[3]=w01.y;
      wsh[4]=w10.x; wsh[5]=w10.y; wsh[6]=w11.x; wsh[7]=w11.y;
    }
  } else {
    if (tid < 4){ float2 w = Wm[i*4+tid]; wsh[tid*2]=w.x; wsh[tid*2+1]=w.y; }
  }
  __syncthreads();
  if (!(mode & MODE_NMF)) return;

  // save T_old for k_vupd's p,q recompute
  if ((tid & 127) < 8){
    int kk = tid & 7;
    Told[(size_t)(n*I_DIM+i)*K_DIM + kk] = t[kk];
  }

  float2 w0 = make_float2(wsh[n*4+0], wsh[n*4+1]);
  float2 w1 = make_float2(wsh[n*4+2], wsh[n*4+3]);
  float p_s[8], q_s[8];
  #pragma unroll
  for (int s=0;s<8;s++){
    float4 x = x_s[s];
    float yre = w0.x*x.x - w0.y*x.y + w1.x*x.z - w1.y*x.w;
    float yim = w0.x*x.y + w0.y*x.x + w1.x*x.w + w1.y*x.z;
    float y2 = yre*yre + yim*yim;
    float r = r_s[s];
    p_s[s] = y2/(r*r + EPS);
    q_s[s] = 1.0f/(r + EPS);
  }
  float aN[8], aD[8];
  #pragma unroll
  for (int k=0;k<8;k++){
    const float4* vp = (const float4*)&Vw[(size_t)(n*K_DIM+k)*J_DIM + jl*8];
    float4 va = vp[0], vb = vp[1];
    aN[k] = p_s[0]*va.x + p_s[1]*va.y + p_s[2]*va.z + p_s[3]*va.w
          + p_s[4]*vb.x + p_s[5]*vb.y + p_s[6]*vb.z + p_s[7]*vb.w;
    aD[k] = q_s[0]*va.x + q_s[1]*va.y + q_s[2]*va.z + q_s[3]*va.w
          + q_s[4]*vb.x + q_s[5]*vb.y + q_s[6]*vb.z + q_s[7]*vb.w;
  }
  #pragma unroll
  for (int k=0;k<8;k++){
    #pragma unroll
    for (int off=32; off>0; off>>=1){
      aN[k] += __shfl_down(aN[k],off);
      aD[k] += __shfl_down(aD[k],off);
    }
  }
  {
    int lane = tid&63, wv = tid>>6;
    if (lane==0){
      #pragma unroll
      for (int k=0;k<8;k++){ redT[wv][k]=aN[k]; redT[wv][k+8]=aD[k]; }
    }
  }
  __syncthreads();
  if ((tid & 127) < 8){
    int kk = tid & 7;
    int wb = (tid>>7)*2;
    float ns = redT[wb][kk]   + redT[wb+1][kk];
    float ds = redT[wb][kk+8] + redT[wb+1][kk+8];
    size_t ti = (size_t)(n*I_DIM+i)*K_DIM + kk;
    Tw[ti] = Tw[ti]*sqrtf(ns/(ds + EPS));
  }
}

// ---- V-update: recompute p,q from (X, T_old, W), reduce over I, scale V ----
// grid (J/4, 2); block 256 = 64 i-lanes x 4 j. Replaces nmf_b + nmf_b2.
__global__ __launch_bounds__(256) void k_vupd(const float4* __restrict__ Xc4,
      const float* __restrict__ Tw, const float* __restrict__ Told,
      float* __restrict__ Vw, const float2* __restrict__ Wm){
  int n = blockIdx.y;
  int tid = threadIdx.x;
  int jj = tid & 3, ii = tid >> 2;
  int j = blockIdx.x*4 + jj;
  float v[8];
  #pragma unroll
  for (int k=0;k<8;k++) v[k] = Vw[(size_t)(n*K_DIM+k)*J_DIM + j];
  float aN[8] = {0,0,0,0,0,0,0,0};
  float aD[8] = {0,0,0,0,0,0,0,0};
  for (int i=ii; i<I_DIM; i+=64){
    const float4* tpo = (const float4*)&Told[(size_t)(n*I_DIM+i)*K_DIM];
    float4 to0 = tpo[0], to1 = tpo[1];
    const float4* tpn = (const float4*)&Tw[(size_t)(n*I_DIM+i)*K_DIM];
    float4 tn0 = tpn[0], tn1 = tpn[1];
    float4 wv = *(const float4*)&Wm[i*4 + n*2];   // (w0.re,w0.im,w1.re,w1.im)
    float4 x  = Xc4[(size_t)i*J_DIM + j];
    float r = to0.x*v[0]+to0.y*v[1]+to0.z*v[2]+to0.w*v[3]
            + to1.x*v[4]+to1.y*v[5]+to1.z*v[6]+to1.w*v[7];
    float yre = wv.x*x.x - wv.y*x.y + wv.z*x.z - wv.w*x.w;
    float yim = wv.x*x.y + wv.y*x.x + wv.z*x.w + wv.w*x.z;
    float y2 = yre*yre + yim*yim;
    float p = y2/(r*r + EPS);
    float q = 1.0f/(r + EPS);
    aN[0]+=tn0.x*p; aN[1]+=tn0.y*p; aN[2]+=tn0.z*p; aN[3]+=tn0.w*p;
    aN[4]+=tn1.x*p; aN[5]+=tn1.y*p; aN[6]+=tn1.z*p; aN[7]+=tn1.w*p;
    aD[0]+=tn0.x*q; aD[1]+=tn0.y*q; aD[2]+=tn0.z*q; aD[3]+=tn0.w*q;
    aD[4]+=tn1.x*q; aD[5]+=tn1.y*q; aD[6]+=tn1.z*q; aD[7]+=tn1.w*q;
  }
  // reduce over ii within wave (lanes with same jj: strides 4)
  #pragma unroll
  for (int k=0;k<8;k++){
    #pragma unroll
    for (int off=32; off>=4; off>>=1){
      aN[k] += __shfl_down(aN[k],off);
      aD[k] += __shfl_down(aD[k],off);
    }
  }
  __shared__ float red[4][4][16];   // [wave][jj][k | k+8]
  int wv_ = tid>>6, lane = tid&63;
  if (lane < 4){
    #pragma unroll
    for (int k=0;k<8;k++){ red[wv_][lane][k]=aN[k]; red[wv_][lane][k+8]=aD[k]; }
  }
  __syncthreads();
  if (tid < 32){
    int jj2 = tid>>3, k = tid&7;
    float num = red[0][jj2][k]+red[1][jj2][k]+red[2][jj2][k]+red[3][jj2][k];
    float den = red[0][jj2][k+8]+red[1][jj2][k+8]+red[2][jj2][k+8]+red[3][jj2][k+8];
    size_t vi = (size_t)(n*K_DIM+k)*J_DIM + blockIdx.x*4 + jj2;
    Vw[vi] *= sqrtf(num/(den + EPS));
  }
}

// ---- final: Y = W @ X, write out [N,J,I,2] (transpose via LDS tile) ----
__global__ void k_final(const float4* __restrict__ Xc4, const float2* __restrict__ Wm,
                        float2* __restrict__ out){
  __shared__ float2 yt[2][32][33];
  int i0 = blockIdx.x*32, j0 = blockIdx.y*32;
  int tx = threadIdx.x, ty = threadIdx.y;
  int j = j0 + tx;
  #pragma unroll
  for (int r=0;r<4;r++){
    int il = ty + r*8; int i = i0 + il;
    if (i < I_DIM){
      float4 x = Xc4[(size_t)i*J_DIM + j];
      #pragma unroll
      for (int n=0;n<2;n++){
        float2 a = Wm[i*4+n*2+0], b = Wm[i*4+n*2+1];
        float2 y;
        y.x = a.x*x.x - a.y*x.y + b.x*x.z - b.y*x.w;
        y.y = a.x*x.y + a.y*x.x + b.x*x.w + b.y*x.z;
        yt[n][tx][il] = y;
      }
    }
  }
  __syncthreads();
  int i = i0 + tx;
  if (i < I_DIM){
    #pragma unroll
    for (int n=0;n<2;n++){
      #pragma unroll
      for (int r=0;r<4;r++){
        int jl = ty + r*8;
        out[(size_t)(n*J_DIM + j0 + jl)*I_DIM + i] = yt[n][jl][tx];
      }
    }
  }
}

extern "C" void kernel_launch(void* const* d_in, const int* in_sizes, int n_in,
                              void* d_out, int out_size, void* d_ws, size_t ws_size,
                              hipStream_t stream){
  const float* X  = (const float*)d_in[0];   // [M,J,I,2]
  const float* T0 = (const float*)d_in[1];   // [I,K,M]
  const float* V0 = (const float*)d_in[2];   // [K,J,M]

  char* ws = (char*)d_ws;
  size_t off = 0;
  auto alloc = [&](size_t bytes)->char*{
    char* p = ws + off; off += (bytes + 255) & ~(size_t)255; return p;
  };
  float4* Xc4  = (float4*)alloc((size_t)I_DIM*J_DIM*sizeof(float4));
  float*  Tw   = (float*) alloc((size_t)2*I_DIM*K_DIM*sizeof(float));
  float*  Told = (float*) alloc((size_t)2*I_DIM*K_DIM*sizeof(float));
  float*  Vw   = (float*) alloc((size_t)2*K_DIM*J_DIM*sizeof(float));
  float2* Wm   = (float2*)alloc((size_t)I_DIM*4*sizeof(float2));

  k_init<<<65, 256, 0, stream>>>(T0, V0, Tw, Vw, Wm);
  k_txpose<<<dim3(33,32), dim3(32,8), 0, stream>>>((const float2*)X, Xc4);
  // A0: NMF T-update of body 0 (W = identity), saves T_old
  k_cda<<<I_DIM, 256, 0, stream>>>(Xc4, Tw, Told, Vw, Wm, MODE_NMF);
  for (int it=0; it<N_ITER; it++){
    k_vupd<<<dim3(J_DIM/4, 2), 256, 0, stream>>>(Xc4, Tw, Told, Vw, Wm);
    int mode = (it < N_ITER-1) ? (MODE_CD|MODE_NMF) : MODE_CD;
    k_cda<<<I_DIM, 256, 0, stream>>>(Xc4, Tw, Told, Vw, Wm, mode);
  }
  k_final<<<dim3(33,32), dim3(32,8), 0, stream>>>(Xc4, Wm, (float2*)d_out);
}

// Round 6
// 311.731 us; speedup vs baseline: 1.2529x; 1.0647x over previous
//
#include <hip/hip_runtime.h>
#include <math.h>

#define I_DIM 1025
#define J_DIM 1024
#define K_DIM 8
#define N_ITER 10
#define EPS 1e-20f
#define REG 1e-6f
#define MODE_CD  1
#define MODE_NMF 2

__device__ __forceinline__ float __frcp(float x){ return __builtin_amdgcn_rcpf(x); }

__device__ __forceinline__ float2 cmul(float2 a, float2 b){
  return make_float2(a.x*b.x - a.y*b.y, a.x*b.y + a.y*b.x);
}
__device__ __forceinline__ float2 cadd(float2 a, float2 b){
  return make_float2(a.x+b.x, a.y+b.y);
}
__device__ __forceinline__ float2 csub(float2 a, float2 b){
  return make_float2(a.x-b.x, a.y-b.y);
}
__device__ __forceinline__ float2 cconj(float2 a){ return make_float2(a.x, -a.y); }
__device__ __forceinline__ float2 cscale(float2 a, float s){ return make_float2(a.x*s, a.y*s); }
__device__ __forceinline__ float2 cdivc(float2 a, float2 d){
  float inv = 1.0f/(d.x*d.x + d.y*d.y);
  return make_float2((a.x*d.x + a.y*d.y)*inv, (a.y*d.x - a.x*d.y)*inv);
}

// ---- init: T -> [n][k][i], V -> [n][k][j], W = identity ----
__global__ void k_init(const float* __restrict__ T0, const float* __restrict__ V0,
                       float* __restrict__ Tw, float* __restrict__ Vw, float2* __restrict__ Wm){
  int tid = blockIdx.x*blockDim.x + threadIdx.x;
  if (tid < 2*K_DIM*I_DIM){
    int i = tid % I_DIM; int rest = tid / I_DIM;
    int k = rest & 7, n = rest >> 3;
    Tw[tid] = T0[(i*K_DIM+k)*2 + n];              // T0 [I,K,M]
  }
  if (tid < 2*K_DIM*J_DIM){
    int n = tid/(K_DIM*J_DIM), rem = tid%(K_DIM*J_DIM);
    int k = rem/J_DIM, j = rem%J_DIM;
    Vw[tid] = V0[(k*J_DIM+j)*2 + n];              // V0 [K,J,M]
  }
  if (tid < I_DIM*4){
    int rc = tid & 3;                              // n*2+m
    Wm[tid] = make_float2((rc==0||rc==3)?1.0f:0.0f, 0.0f);
  }
}

// ---- transpose X [M,J,I,2] -> Xc4 [I][J] float4 = (x0.re,x0.im,x1.re,x1.im) ----
__global__ void k_txpose(const float2* __restrict__ Xin, float4* __restrict__ Xc4){
  __shared__ float4 tile[32][33];
  int i0 = blockIdx.x*32, j0 = blockIdx.y*32;
  int tx = threadIdx.x, ty = threadIdx.y;
  #pragma unroll
  for (int r=0;r<4;r++){
    int jl = ty + r*8; int i = i0 + tx;
    if (i < I_DIM){
      float2 a = Xin[(size_t)(0*J_DIM + j0 + jl)*I_DIM + i];
      float2 b = Xin[(size_t)(1*J_DIM + j0 + jl)*I_DIM + i];
      tile[jl][tx] = make_float4(a.x, a.y, b.x, b.y);
    }
  }
  __syncthreads();
  #pragma unroll
  for (int r=0;r<4;r++){
    int il = ty + r*8; int i = i0 + il;
    if (i < I_DIM) Xc4[(size_t)i*J_DIM + j0 + tx] = tile[tx][il];
  }
}

// ---- fused: [CD + 2x2 solve -> W_i] then [NMF T-update for next body] ----
// Thread owns j_s = jl + 128*s (s=0..7): X float4 loads coalesced per s,
// V scalar loads lane-consecutive (L1-resident).
__global__ __launch_bounds__(256) void k_cda(const float4* __restrict__ Xc4,
      float* __restrict__ Tw, float* __restrict__ Told, const float* __restrict__ Vw,
      float2* __restrict__ Wm, int mode){
  int i = blockIdx.x, tid = threadIdx.x;
  int n = tid >> 7, jl = tid & 127;     // waves 0,1 -> n=0; waves 2,3 -> n=1
  __shared__ float redD[4][4];
  __shared__ float redT[4][16];
  __shared__ float wsh[8];

  float t[8];
  #pragma unroll
  for (int k=0;k<8;k++) t[k] = Tw[(size_t)(n*K_DIM+k)*I_DIM + i];   // 2-line broadcast

  const float* vb = Vw + (size_t)(n*K_DIM)*J_DIM + jl;
  float r_s[8] = {0,0,0,0,0,0,0,0};
  #pragma unroll
  for (int k=0;k<8;k++){
    #pragma unroll
    for (int s=0;s<8;s++) r_s[s] += t[k]*vb[k*J_DIM + 128*s];
  }
  float q_s[8];
  #pragma unroll
  for (int s=0;s<8;s++) q_s[s] = __frcp(r_s[s] + EPS);

  const float4* xb = Xc4 + (size_t)i*J_DIM + jl;
  float4 x_s[8];
  #pragma unroll
  for (int s=0;s<8;s++) x_s[s] = xb[128*s];     // coalesced

  if (mode & MODE_CD){
    float d00=0.0f, d11=0.0f, dre=0.0f, dim_=0.0f;
    #pragma unroll
    for (int s=0;s<8;s++){
      float4 x = x_s[s]; float q = q_s[s];
      d00 += (x.x*x.x + x.y*x.y)*q;
      d11 += (x.z*x.z + x.w*x.w)*q;
      dre += (x.x*x.z + x.y*x.w)*q;   // Re(x0*conj(x1))
      dim_ += (x.y*x.z - x.x*x.w)*q;  // Im(x0*conj(x1))
    }
    #pragma unroll
    for (int off=32; off>0; off>>=1){
      d00 += __shfl_down(d00,off); d11 += __shfl_down(d11,off);
      dre += __shfl_down(dre,off); dim_ += __shfl_down(dim_,off);
    }
    {
      int lane = tid&63, wv = tid>>6;
      if (lane==0){ redD[wv][0]=d00; redD[wv][1]=d11; redD[wv][2]=dre; redD[wv][3]=dim_; }
    }
    __syncthreads();
    if (tid==0){
      const float invJ = 1.0f/(float)J_DIM;
      float D[2][4];
      #pragma unroll
      for (int c=0;c<4;c++){
        D[0][c] = (redD[0][c]+redD[1][c])*invJ;
        D[1][c] = (redD[2][c]+redD[3][c])*invJ;
      }
      float2 w00 = Wm[i*4+0], w01 = Wm[i*4+1], w10 = Wm[i*4+2], w11 = Wm[i*4+3];
      #pragma unroll
      for (int nn=0;nn<2;nn++){
        float d00_ = D[nn][0] + REG, d11_ = D[nn][1] + REG;
        float2 d01 = make_float2(D[nn][2], D[nn][3]);
        float2 d10 = cconj(d01);
        float2 A00 = cadd(cscale(w00, d00_), cmul(w01, d10));
        float2 A01 = cadd(cmul(w00, d01), cscale(w01, d11_));
        float2 A10 = cadd(cscale(w10, d00_), cmul(w11, d10));
        float2 A11 = cadd(cmul(w10, d01), cscale(w11, d11_));
        float2 det = csub(cmul(A00,A11), cmul(A01,A10));
        float2 bu0, bu1;
        if (nn==0){ bu0 = A11; bu1 = make_float2(-A10.x, -A10.y); }
        else      { bu0 = make_float2(-A01.x, -A01.y); bu1 = A00; }
        float2 b0 = cdivc(bu0, det);
        float2 b1 = cdivc(bu1, det);
        float quad = d00_*(b0.x*b0.x + b0.y*b0.y) + d11_*(b1.x*b1.x + b1.y*b1.y);
        float2 u = cmul(d01, b1);
        quad += 2.0f*(b0.x*u.x + b0.y*u.y);
        float inv = 1.0f/sqrtf(quad + EPS);
        float2 wn0 = make_float2(b0.x*inv, -b0.y*inv);
        float2 wn1 = make_float2(b1.x*inv, -b1.y*inv);
        if (nn==0){ w00=wn0; w01=wn1; } else { w10=wn0; w11=wn1; }
      }
      Wm[i*4+0]=w00; Wm[i*4+1]=w01; Wm[i*4+2]=w10; Wm[i*4+3]=w11;
      wsh[0]=w00.x; wsh[1]=w00.y; wsh[2]=w01.x; wsh[3]=w01.y;
      wsh[4]=w10.x; wsh[5]=w10.y; wsh[6]=w11.x; wsh[7]=w11.y;
    }
  } else {
    if (tid < 4){ float2 w = Wm[i*4+tid]; wsh[tid*2]=w.x; wsh[tid*2+1]=w.y; }
  }
  __syncthreads();
  if (!(mode & MODE_NMF)) return;

  // save T_old for k_vupd's p,q recompute
  if ((tid & 127) < 8){
    int kk = tid & 7;
    Told[(size_t)(n*K_DIM+kk)*I_DIM + i] = t[kk];
  }

  float2 w0 = make_float2(wsh[n*4+0], wsh[n*4+1]);
  float2 w1 = make_float2(wsh[n*4+2], wsh[n*4+3]);
  float p_s[8];
  #pragma unroll
  for (int s=0;s<8;s++){
    float4 x = x_s[s];
    float yre = w0.x*x.x - w0.y*x.y + w1.x*x.z - w1.y*x.w;
    float yim = w0.x*x.y + w0.y*x.x + w1.x*x.w + w1.y*x.z;
    float q = q_s[s];
    p_s[s] = (yre*yre + yim*yim)*q*q;
  }
  float aN[8], aD[8];
  #pragma unroll
  for (int k=0;k<8;k++){
    float sn = 0.0f, sd = 0.0f;
    #pragma unroll
    for (int s=0;s<8;s++){
      float v = vb[k*J_DIM + 128*s];
      sn += p_s[s]*v; sd += q_s[s]*v;
    }
    aN[k] = sn; aD[k] = sd;
  }
  #pragma unroll
  for (int k=0;k<8;k++){
    #pragma unroll
    for (int off=32; off>0; off>>=1){
      aN[k] += __shfl_down(aN[k],off);
      aD[k] += __shfl_down(aD[k],off);
    }
  }
  {
    int lane = tid&63, wv = tid>>6;
    if (lane==0){
      #pragma unroll
      for (int k=0;k<8;k++){ redT[wv][k]=aN[k]; redT[wv][k+8]=aD[k]; }
    }
  }
  __syncthreads();
  if ((tid & 127) < 8){
    int kk = tid & 7;
    int wb = (tid>>7)*2;
    float ns = redT[wb][kk]   + redT[wb+1][kk];
    float ds = redT[wb][kk+8] + redT[wb+1][kk+8];
    size_t ti = (size_t)(n*K_DIM+kk)*I_DIM + i;
    Tw[ti] = Tw[ti]*sqrtf(ns*__frcp(ds + EPS));
  }
}

// ---- V-update: recompute p,q from (X, T_old, W), reduce over I, scale V ----
// grid (J/4, 2); block 256 = 64 i-lanes x 4 j. T in [n][k][i]: coalesced.
__global__ __launch_bounds__(256) void k_vupd(const float4* __restrict__ Xc4,
      const float* __restrict__ Tw, const float* __restrict__ Told,
      float* __restrict__ Vw, const float2* __restrict__ Wm){
  int n = blockIdx.y;
  int tid = threadIdx.x;
  int jj = tid & 3, ii = tid >> 2;
  int j = blockIdx.x*4 + jj;
  float v[8];
  #pragma unroll
  for (int k=0;k<8;k++) v[k] = Vw[(size_t)(n*K_DIM+k)*J_DIM + j];
  float aN[8] = {0,0,0,0,0,0,0,0};
  float aD[8] = {0,0,0,0,0,0,0,0};
  const float* tob = Told + (size_t)(n*K_DIM)*I_DIM;
  const float* tnb = Tw   + (size_t)(n*K_DIM)*I_DIM;
  #pragma unroll 2
  for (int i=ii; i<I_DIM; i+=64){
    float to[8], tn[8];
    #pragma unroll
    for (int k=0;k<8;k++){ to[k] = tob[k*I_DIM + i]; tn[k] = tnb[k*I_DIM + i]; }
    float4 wv = *(const float4*)&Wm[i*4 + n*2];   // (w0.re,w0.im,w1.re,w1.im)
    float4 x  = Xc4[(size_t)i*J_DIM + j];
    float r = to[0]*v[0]+to[1]*v[1]+to[2]*v[2]+to[3]*v[3]
            + to[4]*v[4]+to[5]*v[5]+to[6]*v[6]+to[7]*v[7];
    float yre = wv.x*x.x - wv.y*x.y + wv.z*x.z - wv.w*x.w;
    float yim = wv.x*x.y + wv.y*x.x + wv.z*x.w + wv.w*x.z;
    float q = __frcp(r + EPS);
    float p = (yre*yre + yim*yim)*q*q;
    #pragma unroll
    for (int k=0;k<8;k++){ aN[k] += tn[k]*p; aD[k] += tn[k]*q; }
  }
  // reduce over ii within wave (lanes with same jj: strides 4)
  #pragma unroll
  for (int k=0;k<8;k++){
    #pragma unroll
    for (int off=32; off>=4; off>>=1){
      aN[k] += __shfl_down(aN[k],off);
      aD[k] += __shfl_down(aD[k],off);
    }
  }
  __shared__ float red[4][4][16];   // [wave][jj][k | k+8]
  int wv_ = tid>>6, lane = tid&63;
  if (lane < 4){
    #pragma unroll
    for (int k=0;k<8;k++){ red[wv_][lane][k]=aN[k]; red[wv_][lane][k+8]=aD[k]; }
  }
  __syncthreads();
  if (tid < 32){
    int jj2 = tid>>3, k = tid&7;
    float num = red[0][jj2][k]+red[1][jj2][k]+red[2][jj2][k]+red[3][jj2][k];
    float den = red[0][jj2][k+8]+red[1][jj2][k+8]+red[2][jj2][k+8]+red[3][jj2][k+8];
    size_t vi = (size_t)(n*K_DIM+k)*J_DIM + blockIdx.x*4 + jj2;
    Vw[vi] *= sqrtf(num*__frcp(den + EPS));
  }
}

// ---- final: Y = W @ X, write out [N,J,I,2] (transpose via LDS tile) ----
__global__ void k_final(const float4* __restrict__ Xc4, const float2* __restrict__ Wm,
                        float2* __restrict__ out){
  __shared__ float2 yt[2][32][33];
  int i0 = blockIdx.x*32, j0 = blockIdx.y*32;
  int tx = threadIdx.x, ty = threadIdx.y;
  int j = j0 + tx;
  #pragma unroll
  for (int r=0;r<4;r++){
    int il = ty + r*8; int i = i0 + il;
    if (i < I_DIM){
      float4 x = Xc4[(size_t)i*J_DIM + j];
      #pragma unroll
      for (int n=0;n<2;n++){
        float2 a = Wm[i*4+n*2+0], b = Wm[i*4+n*2+1];
        float2 y;
        y.x = a.x*x.x - a.y*x.y + b.x*x.z - b.y*x.w;
        y.y = a.x*x.y + a.y*x.x + b.x*x.w + b.y*x.z;
        yt[n][tx][il] = y;
      }
    }
  }
  __syncthreads();
  int i = i0 + tx;
  if (i < I_DIM){
    #pragma unroll
    for (int n=0;n<2;n++){
      #pragma unroll
      for (int r=0;r<4;r++){
        int jl = ty + r*8;
        out[(size_t)(n*J_DIM + j0 + jl)*I_DIM + i] = yt[n][jl][tx];
      }
    }
  }
}

extern "C" void kernel_launch(void* const* d_in, const int* in_sizes, int n_in,
                              void* d_out, int out_size, void* d_ws, size_t ws_size,
                              hipStream_t stream){
  const float* X  = (const float*)d_in[0];   // [M,J,I,2]
  const float* T0 = (const float*)d_in[1];   // [I,K,M]
  const float* V0 = (const float*)d_in[2];   // [K,J,M]

  char* ws = (char*)d_ws;
  size_t off = 0;
  auto alloc = [&](size_t bytes)->char*{
    char* p = ws + off; off += (bytes + 255) & ~(size_t)255; return p;
  };
  float4* Xc4  = (float4*)alloc((size_t)I_DIM*J_DIM*sizeof(float4));
  float*  Tw   = (float*) alloc((size_t)2*K_DIM*I_DIM*sizeof(float));
  float*  Told = (float*) alloc((size_t)2*K_DIM*I_DIM*sizeof(float));
  float*  Vw   = (float*) alloc((size_t)2*K_DIM*J_DIM*sizeof(float));
  float2* Wm   = (float2*)alloc((size_t)I_DIM*4*sizeof(float2));

  k_init<<<65, 256, 0, stream>>>(T0, V0, Tw, Vw, Wm);
  k_txpose<<<dim3(33,32), dim3(32,8), 0, stream>>>((const float2*)X, Xc4);
  // A0: NMF T-update of body 0 (W = identity), saves T_old
  k_cda<<<I_DIM, 256, 0, stream>>>(Xc4, Tw, Told, Vw, Wm, MODE_NMF);
  for (int it=0; it<N_ITER; it++){
    k_vupd<<<dim3(J_DIM/4, 2), 256, 0, stream>>>(Xc4, Tw, Told, Vw, Wm);
    int mode = (it < N_ITER-1) ? (MODE_CD|MODE_NMF) : MODE_CD;
    k_cda<<<I_DIM, 256, 0, stream>>>(Xc4, Tw, Told, Vw, Wm, mode);
  }
  k_final<<<dim3(33,32), dim3(32,8), 0, stream>>>(Xc4, Wm, (float2*)d_out);
}